// Round 1
// 321.105 us; speedup vs baseline: 1.4179x; 1.4179x over previous
//
#include <hip/hip_runtime.h>
#include <hip/hip_bf16.h>
#include <stdint.h>

// Problem constants
#define B_     8
#define CSW    241      // coarse_scores (B,241,241)
#define GW     121      // grid (B,121,121)
#define NPB    14641    // 121*121 per batch
#define KSEL   256
#define TOTG   117128   // 8*14641 gumbel count

// top-k split
#define NSEG   16
#define SEGLEN 916      // ceil(14641/16); last segment has 901

// Output layout (floats): patches (8,256,3,64,64)=25165824,
// label_patches (8,256,1,64,64)=8388608, coords (8,256,2)=4096
#define PATCH_OFF   0
#define LABEL_OFF   25165824
#define COORD_OFF   33554432

// scratch inside d_out (floats), all dead before gather overwrites
#define FG_OFF    0           // 8*65536 = 524288 floats
#define CS_OFF    524288      // 8*58081 = 464648 floats
#define FLAT_OFF  988936      // 8*14641 = 117128 floats
#define MM_OFF    1106064     // 16 floats
#define KEY_OFF   1106080     // byte offset 4424320 (8-aligned); 8*14641 u64
#define CAND_OFF  1340336     // = KEY_OFF + 2*TOTG; 8*16*256 u64 = 65536 floats

// ---------------- fg = 4x4 stride-4 block mean of labels ----------------
// XLA CPU reduce order: flat sequential chain, row-major over (dy,dx), init 0.
__global__ void k_fg(const float* __restrict__ labels, float* __restrict__ fg) {
  int idx = blockIdx.x * 256 + threadIdx.x;          // < 8*256*256
  int b = idx >> 16; int rem = idx & 65535;
  int oy = rem >> 8; int ox = rem & 255;
  const float* p = labels + (size_t)b * 1048576 + (size_t)oy * 4096 + ox * 4;
  float acc = 0.0f;
  #pragma unroll
  for (int dy = 0; dy < 4; ++dy) {
    const float* r = p + dy * 1024;
    #pragma unroll
    for (int dx = 0; dx < 4; ++dx) acc = __fadd_rn(acc, r[dx]);
  }
  fg[idx] = __fdiv_rn(acc, 16.0f);                   // exact (pow2)
}

// ---------------- coarse_scores = 16x16 stride-1 window mean ----------------
// XLA CPU reduce_window: naive nested loop, flat sequential (wy outer, wx
// inner), init 0.
__global__ void k_cs(const float* __restrict__ fg, float* __restrict__ cs) {
  int idx = blockIdx.x * 256 + threadIdx.x;
  if (idx >= B_ * CSW * CSW) return;
  int b = idx / (CSW * CSW); int rem = idx % (CSW * CSW);
  int oy = rem / CSW; int ox = rem % CSW;
  const float* p = fg + (size_t)b * 65536 + (size_t)oy * 256 + ox;
  float acc = 0.0f;
  for (int wy = 0; wy < 16; ++wy) {
    const float* r = p + wy * 256;
    #pragma unroll
    for (int wx = 0; wx < 16; ++wx) acc = __fadd_rn(acc, r[wx]);
  }
  cs[idx] = __fdiv_rn(acc, 256.0f);                  // exact (pow2)
}

// ---------------- bilinear resize 241x241 -> 121x121, fp32 exact order ----------------
__global__ void k_resize(const float* __restrict__ cs, float* __restrict__ flat) {
  int idx = blockIdx.x * 256 + threadIdx.x;
  if (idx >= B_ * NPB) return;
  int b = idx / NPB; int rem = idx % NPB;
  int oy = rem / GW; int ox = rem % GW;
  const float SCALE = (float)(241.0 / 121.0);        // f64 const -> f32

  float cy = __fsub_rn(__fmul_rn(__fadd_rn((float)oy, 0.5f), SCALE), 0.5f);
  cy = fminf(fmaxf(cy, 0.0f), 240.0f);
  int y0 = (int)floorf(cy); int y1 = min(y0 + 1, 240);
  float wy = __fsub_rn(cy, (float)y0);

  float cx = __fsub_rn(__fmul_rn(__fadd_rn((float)ox, 0.5f), SCALE), 0.5f);
  cx = fminf(fmaxf(cx, 0.0f), 240.0f);
  int x0 = (int)floorf(cx); int x1 = min(x0 + 1, 240);
  float wx = __fsub_rn(cx, (float)x0);

  const float* base = cs + (size_t)b * (CSW * CSW);
  float v00 = base[y0 * CSW + x0];
  float v01 = base[y0 * CSW + x1];
  float v10 = base[y1 * CSW + x0];
  float v11 = base[y1 * CSW + x1];
  float omwx = __fsub_rn(1.0f, wx), omwy = __fsub_rn(1.0f, wy);
  float top = __fadd_rn(__fmul_rn(v00, omwx), __fmul_rn(v01, wx));
  float bot = __fadd_rn(__fmul_rn(v10, omwx), __fmul_rn(v11, wx));
  flat[idx] = __fadd_rn(__fmul_rn(top, omwy), __fmul_rn(bot, wy));
}

// ---------------- per-batch min/max (order-free, exact) ----------------
__global__ void k_minmax(const float* __restrict__ flat, float* __restrict__ mm) {
  __shared__ float smn[256], smx[256];
  int b = blockIdx.x, tid = threadIdx.x;
  float mn = 3.402823466e38f, mx = -3.402823466e38f;
  for (int j = tid; j < NPB; j += 256) {
    float v = flat[(size_t)b * NPB + j];
    mn = fminf(mn, v); mx = fmaxf(mx, v);
  }
  smn[tid] = mn; smx[tid] = mx; __syncthreads();
  for (int s = 128; s > 0; s >>= 1) {
    if (tid < s) {
      smn[tid] = fminf(smn[tid], smn[tid + s]);
      smx[tid] = fmaxf(smx[tid], smx[tid + s]);
    }
    __syncthreads();
  }
  if (tid == 0) { mm[b] = smn[0]; mm[8 + b] = smx[0]; }
}

// ---------------- threefry2x32, key (0,42), both output lanes ----------------
__device__ __forceinline__ void tf2(unsigned c0, unsigned c1,
                                    unsigned* o0, unsigned* o1) {
  const unsigned ks0 = 0u, ks1 = 42u, ks2 = 0x1BD11BDAu ^ 0u ^ 42u;
  unsigned x0 = c0 + ks0, x1 = c1 + ks1;
#define RND(r) { x0 += x1; x1 = (x1 << r) | (x1 >> (32 - r)); x1 ^= x0; }
  RND(13) RND(15) RND(26) RND(6)   x0 += ks1; x1 += ks2 + 1u;
  RND(17) RND(29) RND(16) RND(24)  x0 += ks2; x1 += ks0 + 2u;
  RND(13) RND(15) RND(26) RND(6)   x0 += ks0; x1 += ks1 + 3u;
  RND(17) RND(29) RND(16) RND(24)  x0 += ks1; x1 += ks2 + 4u;
  RND(13) RND(15) RND(26) RND(6)   x0 += ks2; x1 += ks0 + 5u;
#undef RND
  *o0 = x0; *o1 = x1;
}

// ---------------- scaled + gumbel -> sortable u64 keys ----------------
// JAX partitionable threefry (default >=0.4.30): counter-mode per element,
// bits[i] = x0 ^ x1 of threefry2x32(key, (hi32(i), lo32(i))) = (0, i).
__global__ void k_keys(const float* __restrict__ flat, const float* __restrict__ mm,
                       unsigned long long* __restrict__ keys) {
  int idx = blockIdx.x * 256 + threadIdx.x;
  if (idx >= TOTG) return;
  int b = idx / NPB; unsigned j = (unsigned)(idx % NPB);
  float smin = mm[b], smax = mm[8 + b];
  float rng = fmaxf(__fsub_rn(smax, smin), 1e-6f);
  float scaled = __fdiv_rn(__fdiv_rn(__fsub_rn(flat[idx], smin), rng), 0.1f);

  unsigned o0, o1;
  tf2(0u, (unsigned)idx, &o0, &o1);
  unsigned bits = o0 ^ o1;

  unsigned m = bits >> 9;
  float u = (m == 0u) ? 1.17549435e-38f
                      : __fsub_rn(__uint_as_float(0x3f800000u | m), 1.0f);
  // g = -log(-log(u)), each log evaluated in f64 then rounded to f32
  float l1 = (float)::log((double)u);
  float a  = -l1;
  float l2 = (float)::log((double)a);
  float g  = -l2;

  float tot = __fadd_rn(scaled, g);
  unsigned s = __float_as_uint(tot);
  unsigned o = (s & 0x80000000u) ? ~s : (s | 0x80000000u);   // monotone float order
  keys[idx] = ((unsigned long long)o << 32) | (unsigned long long)(j ^ 0xFFFFFFFFu);
}

// ---------------- phase A: per-segment sort, emit top-256 (desc) ----------------
// 8*16 = 128 blocks. Each block sorts a 1024-padded segment of 916 keys in
// LDS (8 KB) and writes its descending top-256. All real keys > 0 (the
// monotone float map can't produce 0 for a finite total), so 0-padding is
// strictly smaller than any real key and 256 < 901 real keys per segment.
__global__ void k_part(const unsigned long long* __restrict__ keys,
                       unsigned long long* __restrict__ cand) {
  __shared__ unsigned long long sm[1024];
  int blk = blockIdx.x;                 // b*16 + s
  int b = blk >> 4, s = blk & 15;
  int base = s * SEGLEN;
  int len = min(SEGLEN, NPB - base);
  const unsigned long long* kb = keys + (size_t)b * NPB + base;
  int tid = threadIdx.x;
  for (int i = tid; i < 1024; i += 256) sm[i] = (i < len) ? kb[i] : 0ull;
  __syncthreads();

  // bitonic sort ascending over 1024
  for (int ksz = 2; ksz <= 1024; ksz <<= 1) {
    for (int j = ksz >> 1; j > 0; j >>= 1) {
      for (int i = tid; i < 1024; i += 256) {
        int ixj = i ^ j;
        if (ixj > i) {
          bool up = ((i & ksz) == 0);
          unsigned long long a = sm[i], c = sm[ixj];
          if ((a > c) == up) { sm[i] = c; sm[ixj] = a; }
        }
      }
      __syncthreads();
    }
  }
  cand[(size_t)blk * 256 + tid] = sm[1023 - tid];   // descending top-256
}

// ---------------- phase B: prune-merge 16 sorted lists -> top-256 ----------------
// Bitonic top-k reduction: for descending sorted A,B (256 each),
// c[i] = max(A[i], B[255-i]) is exactly the top-256 multiset of A∪B and is
// bitonic; an 8-level bitonic merge re-sorts it descending. 4 tree rounds.
__global__ void k_merge(const unsigned long long* __restrict__ cand,
                        float* __restrict__ coords) {
  __shared__ unsigned long long sm[4096];
  int b = blockIdx.x, tid = threadIdx.x;
  const unsigned long long* cb = cand + (size_t)b * 4096;
  for (int t = tid; t < 4096; t += 256) sm[t] = cb[t];
  __syncthreads();

  int g = 1;                            // slot gap between live lists
  for (int m = NSEG; m > 1; m >>= 1, g <<= 1) {
    int half = m >> 1;
    // prune step: pair p = (slot 2p*g, slot (2p+1)*g) -> top-256 into A, bitonic
    for (int q = tid; q < half * 256; q += 256) {
      int p = q >> 8, i = q & 255;
      int A = (2 * p) * g * 256, Bb = (2 * p + 1) * g * 256;
      unsigned long long a = sm[A + i], c = sm[Bb + 255 - i];
      sm[A + i] = a > c ? a : c;
    }
    __syncthreads();
    // clean: bitonic merge (descending) of each surviving 256-list
    for (int j = 128; j > 0; j >>= 1) {
      for (int q = tid; q < half * 128; q += 256) {
        int p = q >> 7, r = q & 127;
        int i = ((r & ~(j - 1)) << 1) | (r & (j - 1));
        int A = (2 * p) * g * 256;
        unsigned long long a = sm[A + i], c = sm[A + i + j];
        if (a < c) { sm[A + i] = c; sm[A + i + j] = a; }
      }
      __syncthreads();
    }
  }

  unsigned long long key = sm[tid];     // descending -> tid = rank
  unsigned j = ((unsigned)(key & 0xFFFFFFFFull)) ^ 0xFFFFFFFFu;
  int row = j / GW, col = j % GW;
  coords[((size_t)b * KSEL + tid) * 2 + 0] = (float)(row * 8);
  coords[((size_t)b * KSEL + tid) * 2 + 1] = (float)(col * 8);
}

// ---------------- gather patches + label patches ----------------
__global__ void k_gather(const float* __restrict__ image, const float* __restrict__ labels,
                         float* __restrict__ out) {
  int bk = blockIdx.x;                 // b*256 + k
  int b = bk >> 8;
  const float* coords = out + COORD_OFF;
  int h = (int)coords[(size_t)bk * 2 + 0];
  int w = (int)coords[(size_t)bk * 2 + 1];

  const float* imgb = image + (size_t)b * 3145728;
  float* po = out + PATCH_OFF + (size_t)bk * 12288;
  for (int t = threadIdx.x; t < 12288; t += 256) {
    int c = t >> 12, rem = t & 4095, y = rem >> 6, x = rem & 63;
    po[t] = imgb[(size_t)c * 1048576 + (size_t)(h + y) * 1024 + (w + x)];
  }
  const float* labb = labels + (size_t)b * 1048576;
  float* lo = out + LABEL_OFF + (size_t)bk * 4096;
  for (int t = threadIdx.x; t < 4096; t += 256) {
    int y = t >> 6, x = t & 63;
    lo[t] = labb[(size_t)(h + y) * 1024 + (w + x)];
  }
}

extern "C" void kernel_launch(void* const* d_in, const int* in_sizes, int n_in,
                              void* d_out, int out_size, void* d_ws, size_t ws_size,
                              hipStream_t stream) {
  const float* image  = (const float*)d_in[0];   // (8,3,1024,1024)
  const float* labels = (const float*)d_in[1];   // (8,1,1024,1024)
  float* out = (float*)d_out;

  float* fg   = out + FG_OFF;
  float* cs   = out + CS_OFF;
  float* flat = out + FLAT_OFF;
  float* mm   = out + MM_OFF;
  unsigned long long* keys = (unsigned long long*)(out + KEY_OFF);
  unsigned long long* cand = (unsigned long long*)(out + CAND_OFF);
  float* coords = out + COORD_OFF;

  k_fg<<<2048, 256, 0, stream>>>(labels, fg);
  k_cs<<<(B_ * CSW * CSW + 255) / 256, 256, 0, stream>>>(fg, cs);
  k_resize<<<(TOTG + 255) / 256, 256, 0, stream>>>(cs, flat);
  k_minmax<<<B_, 256, 0, stream>>>(flat, mm);
  k_keys<<<(TOTG + 255) / 256, 256, 0, stream>>>(flat, mm, keys);
  k_part<<<B_ * NSEG, 256, 0, stream>>>(keys, cand);
  k_merge<<<B_, 256, 0, stream>>>(cand, coords);
  k_gather<<<2048, 256, 0, stream>>>(image, labels, out);
}

// Round 2
// 309.862 us; speedup vs baseline: 1.4694x; 1.0363x over previous
//
#include <hip/hip_runtime.h>
#include <hip/hip_bf16.h>
#include <stdint.h>

// Problem constants
#define B_     8
#define CSW    241      // coarse_scores (B,241,241)
#define CSG    61       // ceil(241/4) output groups per row in k_cs
#define GW     121      // grid (B,121,121)
#define NPB    14641    // 121*121 per batch
#define KSEL   256
#define TOTG   117128   // 8*14641 gumbel count

// top-k split
#define NSEG   16
#define SEGLEN 916      // ceil(14641/16); last segment has 901

// Output layout (floats): patches (8,256,3,64,64)=25165824,
// label_patches (8,256,1,64,64)=8388608, coords (8,256,2)=4096
#define PATCH_OFF   0
#define LABEL_OFF   25165824
#define COORD_OFF   33554432

// scratch inside d_out (floats), all dead before gather overwrites
#define FG_OFF    0           // 8*65536 = 524288 floats
#define CS_OFF    524288      // 8*58081 = 464648 floats
#define FLAT_OFF  988936      // 8*14641 = 117128 floats
#define MM_OFF    1106064     // 16 u32 (encoded min[8], max[8])
#define CAND_OFF  1340336     // 8*16*256 u64 = 65536 floats

// monotone float<->uint order encoding (same map used for sort keys)
__device__ __forceinline__ unsigned enc_f(float f) {
  unsigned s = __float_as_uint(f);
  return (s & 0x80000000u) ? ~s : (s | 0x80000000u);
}
__device__ __forceinline__ float dec_f(unsigned o) {
  unsigned s = (o & 0x80000000u) ? (o & 0x7FFFFFFFu) : ~o;
  return __uint_as_float(s);
}

// ---------------- fg = 4x4 stride-4 block mean of labels ----------------
// XLA CPU reduce order: flat sequential chain, row-major over (dy,dx), init 0.
// float4 row loads (16B aligned: ox*16 bytes), adds in exact x-order.
__global__ void k_fg(const float* __restrict__ labels, float* __restrict__ fg) {
  int idx = blockIdx.x * 256 + threadIdx.x;          // < 8*256*256
  int b = idx >> 16; int rem = idx & 65535;
  int oy = rem >> 8; int ox = rem & 255;
  const float4* p = (const float4*)(labels + (size_t)b * 1048576 +
                                    (size_t)oy * 4096 + ox * 4);
  float acc = 0.0f;
  #pragma unroll
  for (int dy = 0; dy < 4; ++dy) {
    float4 v = p[dy * 256];                          // row stride 1024 floats
    acc = __fadd_rn(acc, v.x); acc = __fadd_rn(acc, v.y);
    acc = __fadd_rn(acc, v.z); acc = __fadd_rn(acc, v.w);
  }
  fg[idx] = __fdiv_rn(acc, 16.0f);                   // exact (pow2)
}

// ---------------- coarse_scores = 16x16 stride-1 window mean ----------------
// Register-blocked: 4 outputs per thread along ox share 19-wide row loads.
// Each output's add chain stays wy-outer / wx-inner, bit-identical to XLA.
// Also initializes the encoded min/max slots for k_resize's atomics.
__global__ void k_cs(const float* __restrict__ fg, float* __restrict__ cs,
                     unsigned* __restrict__ mm) {
  if (blockIdx.x == 0 && threadIdx.x < 16)
    mm[threadIdx.x] = (threadIdx.x < 8) ? 0xFFFFFFFFu : 0u;   // min=+inf, max=-inf

  int idx = blockIdx.x * 256 + threadIdx.x;
  const int TOT = B_ * CSW * CSG;                    // 117608
  if (idx >= TOT) return;
  int b = idx / (CSW * CSG); int rem = idx % (CSW * CSG);
  int oy = rem / CSG; int ox0 = (rem % CSG) * 4;
  int nk = min(4, CSW - ox0);                        // 4, or 1 at ox0=240
  int lv = nk + 15;                                  // valid loads per row
  const float* p = fg + (size_t)b * 65536 + (size_t)oy * 256 + ox0;

  float acc[4] = {0.0f, 0.0f, 0.0f, 0.0f};
  for (int wy = 0; wy < 16; ++wy) {
    const float* r = p + wy * 256;
    float v[19];
    #pragma unroll
    for (int x = 0; x < 19; ++x) { v[x] = 0.0f; if (x < lv) v[x] = r[x]; }
    #pragma unroll
    for (int k = 0; k < 4; ++k) {
      if (k < nk) {
        #pragma unroll
        for (int wx = 0; wx < 16; ++wx) acc[k] = __fadd_rn(acc[k], v[k + wx]);
      }
    }
  }
  float* co = cs + (size_t)b * (CSW * CSW) + (size_t)oy * CSW + ox0;
  #pragma unroll
  for (int k = 0; k < 4; ++k)
    if (k < nk) co[k] = __fdiv_rn(acc[k], 256.0f);   // exact (pow2)
}

// ---------------- bilinear resize 241x241 -> 121x121 + fused min/max ----------------
// grid (58, 8): blockIdx.y = batch, so each block reduces a single batch.
__global__ void k_resize(const float* __restrict__ cs, float* __restrict__ flat,
                         unsigned* __restrict__ mm) {
  __shared__ unsigned smn[256], smx[256];
  int b = blockIdx.y;
  int rem = blockIdx.x * 256 + threadIdx.x;
  int tid = threadIdx.x;
  unsigned mn = 0xFFFFFFFFu, mx = 0u;

  if (rem < NPB) {
    int oy = rem / GW; int ox = rem % GW;
    const float SCALE = (float)(241.0 / 121.0);      // f64 const -> f32

    float cy = __fsub_rn(__fmul_rn(__fadd_rn((float)oy, 0.5f), SCALE), 0.5f);
    cy = fminf(fmaxf(cy, 0.0f), 240.0f);
    int y0 = (int)floorf(cy); int y1 = min(y0 + 1, 240);
    float wy = __fsub_rn(cy, (float)y0);

    float cx = __fsub_rn(__fmul_rn(__fadd_rn((float)ox, 0.5f), SCALE), 0.5f);
    cx = fminf(fmaxf(cx, 0.0f), 240.0f);
    int x0 = (int)floorf(cx); int x1 = min(x0 + 1, 240);
    float wx = __fsub_rn(cx, (float)x0);

    const float* base = cs + (size_t)b * (CSW * CSW);
    float v00 = base[y0 * CSW + x0];
    float v01 = base[y0 * CSW + x1];
    float v10 = base[y1 * CSW + x0];
    float v11 = base[y1 * CSW + x1];
    float omwx = __fsub_rn(1.0f, wx), omwy = __fsub_rn(1.0f, wy);
    float top = __fadd_rn(__fmul_rn(v00, omwx), __fmul_rn(v01, wx));
    float bot = __fadd_rn(__fmul_rn(v10, omwx), __fmul_rn(v11, wx));
    float val = __fadd_rn(__fmul_rn(top, omwy), __fmul_rn(bot, wy));
    flat[(size_t)b * NPB + rem] = val;
    unsigned o = enc_f(val);
    mn = o; mx = o;
  }
  smn[tid] = mn; smx[tid] = mx; __syncthreads();
  for (int s = 128; s > 0; s >>= 1) {
    if (tid < s) {
      smn[tid] = min(smn[tid], smn[tid + s]);
      smx[tid] = max(smx[tid], smx[tid + s]);
    }
    __syncthreads();
  }
  if (tid == 0) {
    atomicMin(&mm[b], smn[0]);                       // device-scope, exact
    atomicMax(&mm[8 + b], smx[0]);
  }
}

// ---------------- threefry2x32, key (0,42), both output lanes ----------------
__device__ __forceinline__ void tf2(unsigned c0, unsigned c1,
                                    unsigned* o0, unsigned* o1) {
  const unsigned ks0 = 0u, ks1 = 42u, ks2 = 0x1BD11BDAu ^ 0u ^ 42u;
  unsigned x0 = c0 + ks0, x1 = c1 + ks1;
#define RND(r) { x0 += x1; x1 = (x1 << r) | (x1 >> (32 - r)); x1 ^= x0; }
  RND(13) RND(15) RND(26) RND(6)   x0 += ks1; x1 += ks2 + 1u;
  RND(17) RND(29) RND(16) RND(24)  x0 += ks2; x1 += ks0 + 2u;
  RND(13) RND(15) RND(26) RND(6)   x0 += ks0; x1 += ks1 + 3u;
  RND(17) RND(29) RND(16) RND(24)  x0 += ks1; x1 += ks2 + 4u;
  RND(13) RND(15) RND(26) RND(6)   x0 += ks2; x1 += ks0 + 5u;
#undef RND
  *o0 = x0; *o1 = x1;
}

// ---------------- phase A: fused keys + per-segment sort, emit top-256 ----------------
// 8*16 = 128 blocks. Each block computes the gumbel-perturbed sort keys for
// its disjoint 916-element segment directly into LDS (no global keys array),
// bitonic-sorts the 1024-padded segment, writes its descending top-256.
// All real keys > 0 (tot is finite -> encoded != 0xFFFFFFFF), so 0-padding
// sorts strictly below; 256 < 901 real keys per segment.
__global__ void k_part(const float* __restrict__ flat, const unsigned* __restrict__ mm,
                       unsigned long long* __restrict__ cand) {
  __shared__ unsigned long long sm[1024];
  int blk = blockIdx.x;                 // b*16 + s
  int b = blk >> 4, s = blk & 15;
  int base = s * SEGLEN;
  int len = min(SEGLEN, NPB - base);
  int tid = threadIdx.x;

  float smin = dec_f(mm[b]), smax = dec_f(mm[8 + b]);
  float rng = fmaxf(__fsub_rn(smax, smin), 1e-6f);

  for (int i = tid; i < 1024; i += 256) {
    unsigned long long kv = 0ull;
    if (i < len) {
      int j = base + i;
      int idx = b * NPB + j;
      float scaled = __fdiv_rn(__fdiv_rn(__fsub_rn(flat[idx], smin), rng), 0.1f);

      // JAX partitionable threefry: bits = x0 ^ x1 of tf2(key=(0,42), ctr=(0,idx))
      unsigned o0, o1;
      tf2(0u, (unsigned)idx, &o0, &o1);
      unsigned bits = o0 ^ o1;

      unsigned m = bits >> 9;
      float u = (m == 0u) ? 1.17549435e-38f
                          : __fsub_rn(__uint_as_float(0x3f800000u | m), 1.0f);
      // g = -log(-log(u)), each log evaluated in f64 then rounded to f32
      float l1 = (float)::log((double)u);
      float a  = -l1;
      float l2 = (float)::log((double)a);
      float g  = -l2;

      float tot = __fadd_rn(scaled, g);
      unsigned o = enc_f(tot);
      kv = ((unsigned long long)o << 32) | (unsigned long long)((unsigned)j ^ 0xFFFFFFFFu);
    }
    sm[i] = kv;
  }
  __syncthreads();

  // bitonic sort ascending over 1024
  for (int ksz = 2; ksz <= 1024; ksz <<= 1) {
    for (int j = ksz >> 1; j > 0; j >>= 1) {
      for (int i = tid; i < 1024; i += 256) {
        int ixj = i ^ j;
        if (ixj > i) {
          bool up = ((i & ksz) == 0);
          unsigned long long a = sm[i], c = sm[ixj];
          if ((a > c) == up) { sm[i] = c; sm[ixj] = a; }
        }
      }
      __syncthreads();
    }
  }
  cand[(size_t)blk * 256 + tid] = sm[1023 - tid];   // descending top-256
}

// ---------------- phase B: prune-merge 16 sorted lists -> top-256 ----------------
// Bitonic top-k reduction: for descending sorted A,B (256 each),
// c[i] = max(A[i], B[255-i]) is exactly the top-256 multiset of A∪B and is
// bitonic; an 8-level bitonic merge re-sorts it descending. 4 tree rounds.
__global__ void k_merge(const unsigned long long* __restrict__ cand,
                        float* __restrict__ coords) {
  __shared__ unsigned long long sm[4096];
  int b = blockIdx.x, tid = threadIdx.x;
  const unsigned long long* cb = cand + (size_t)b * 4096;
  for (int t = tid; t < 4096; t += 256) sm[t] = cb[t];
  __syncthreads();

  int g = 1;                            // slot gap between live lists
  for (int m = NSEG; m > 1; m >>= 1, g <<= 1) {
    int half = m >> 1;
    // prune step: pair p = (slot 2p*g, slot (2p+1)*g) -> top-256 into A, bitonic
    for (int q = tid; q < half * 256; q += 256) {
      int p = q >> 8, i = q & 255;
      int A = (2 * p) * g * 256, Bb = (2 * p + 1) * g * 256;
      unsigned long long a = sm[A + i], c = sm[Bb + 255 - i];
      sm[A + i] = a > c ? a : c;
    }
    __syncthreads();
    // clean: bitonic merge (descending) of each surviving 256-list
    for (int j = 128; j > 0; j >>= 1) {
      for (int q = tid; q < half * 128; q += 256) {
        int p = q >> 7, r = q & 127;
        int i = ((r & ~(j - 1)) << 1) | (r & (j - 1));
        int A = (2 * p) * g * 256;
        unsigned long long a = sm[A + i], c = sm[A + i + j];
        if (a < c) { sm[A + i] = c; sm[A + i + j] = a; }
      }
      __syncthreads();
    }
  }

  unsigned long long key = sm[tid];     // descending -> tid = rank
  unsigned j = ((unsigned)(key & 0xFFFFFFFFull)) ^ 0xFFFFFFFFu;
  int row = j / GW, col = j % GW;
  coords[((size_t)b * KSEL + tid) * 2 + 0] = (float)(row * 8);
  coords[((size_t)b * KSEL + tid) * 2 + 1] = (float)(col * 8);
}

// ---------------- gather patches + label patches (float4) ----------------
// w = col*8 -> 32B-aligned row starts; all accesses are aligned float4.
__global__ void k_gather(const float* __restrict__ image, const float* __restrict__ labels,
                         float* __restrict__ out) {
  int bk = blockIdx.x;                 // b*256 + k
  int b = bk >> 8;
  const float* coords = out + COORD_OFF;
  int h = (int)coords[(size_t)bk * 2 + 0];
  int w = (int)coords[(size_t)bk * 2 + 1];

  const float* imgb = image + (size_t)b * 3145728;
  float4* po = (float4*)(out + PATCH_OFF + (size_t)bk * 12288);
  for (int t = threadIdx.x; t < 3072; t += 256) {
    int c = t >> 10, rem = t & 1023, y = rem >> 4, x4 = rem & 15;
    po[t] = *(const float4*)(imgb + (size_t)c * 1048576 +
                             (size_t)(h + y) * 1024 + w + x4 * 4);
  }
  const float* labb = labels + (size_t)b * 1048576;
  float4* lo = (float4*)(out + LABEL_OFF + (size_t)bk * 4096);
  for (int t = threadIdx.x; t < 1024; t += 256) {
    int y = t >> 4, x4 = t & 15;
    lo[t] = *(const float4*)(labb + (size_t)(h + y) * 1024 + w + x4 * 4);
  }
}

extern "C" void kernel_launch(void* const* d_in, const int* in_sizes, int n_in,
                              void* d_out, int out_size, void* d_ws, size_t ws_size,
                              hipStream_t stream) {
  const float* image  = (const float*)d_in[0];   // (8,3,1024,1024)
  const float* labels = (const float*)d_in[1];   // (8,1,1024,1024)
  float* out = (float*)d_out;

  float* fg   = out + FG_OFF;
  float* cs   = out + CS_OFF;
  float* flat = out + FLAT_OFF;
  unsigned* mm = (unsigned*)(out + MM_OFF);
  unsigned long long* cand = (unsigned long long*)(out + CAND_OFF);
  float* coords = out + COORD_OFF;

  k_fg<<<2048, 256, 0, stream>>>(labels, fg);
  k_cs<<<(B_ * CSW * CSG + 255) / 256, 256, 0, stream>>>(fg, cs, mm);
  k_resize<<<dim3((NPB + 255) / 256, B_), 256, 0, stream>>>(cs, flat, mm);
  k_part<<<B_ * NSEG, 256, 0, stream>>>(flat, mm, cand);
  k_merge<<<B_, 256, 0, stream>>>(cand, coords);
  k_gather<<<2048, 256, 0, stream>>>(image, labels, out);
}

// Round 4
// 293.842 us; speedup vs baseline: 1.5495x; 1.0545x over previous
//
#include <hip/hip_runtime.h>
#include <hip/hip_bf16.h>
#include <stdint.h>

// Problem constants
#define B_     8
#define CSW    241      // coarse_scores (B,241,241)
#define CSG    61       // ceil(241/4) output groups per row in k_cs
#define GW     121      // grid (B,121,121)
#define NPB    14641    // 121*121 per batch
#define KSEL   256
#define TOTG   117128   // 8*14641 gumbel count

// top-k split
#define NSEG   16
#define SEGLEN 916      // ceil(14641/16); last segment has 901

// Output layout (floats): patches (8,256,3,64,64)=25165824,
// label_patches (8,256,1,64,64)=8388608, coords (8,256,2)=4096
#define PATCH_OFF   0
#define LABEL_OFF   25165824
#define COORD_OFF   33554432

// scratch inside d_out (floats), all dead before gather overwrites
#define FG_OFF    0           // 8*65536 = 524288 floats
#define CS_OFF    524288      // 8*58081 = 464648 floats
#define FLAT_OFF  988936      // 8*14641 = 117128 floats
#define MM_OFF    1106064     // 16 u32 (encoded min[8], max[8])
#define CAND_OFF  1340336     // 8*16*256 u64 = 65536 floats (byte off 5361344, 16B aligned)

// native 4-float vector for nontemporal builtins (same layout as float4)
typedef float floatx4 __attribute__((ext_vector_type(4)));

// monotone float<->uint order encoding (same map used for sort keys)
__device__ __forceinline__ unsigned enc_f(float f) {
  unsigned s = __float_as_uint(f);
  return (s & 0x80000000u) ? ~s : (s | 0x80000000u);
}
__device__ __forceinline__ float dec_f(unsigned o) {
  unsigned s = (o & 0x80000000u) ? (o & 0x7FFFFFFFu) : ~o;
  return __uint_as_float(s);
}

// ---------------- fg = 4x4 stride-4 block mean of labels ----------------
// XLA CPU reduce order: flat sequential chain, row-major over (dy,dx), init 0.
__global__ void k_fg(const float* __restrict__ labels, float* __restrict__ fg) {
  int idx = blockIdx.x * 256 + threadIdx.x;          // < 8*256*256
  int b = idx >> 16; int rem = idx & 65535;
  int oy = rem >> 8; int ox = rem & 255;
  const float4* p = (const float4*)(labels + (size_t)b * 1048576 +
                                    (size_t)oy * 4096 + ox * 4);
  float acc = 0.0f;
  #pragma unroll
  for (int dy = 0; dy < 4; ++dy) {
    float4 v = p[dy * 256];                          // row stride 1024 floats
    acc = __fadd_rn(acc, v.x); acc = __fadd_rn(acc, v.y);
    acc = __fadd_rn(acc, v.z); acc = __fadd_rn(acc, v.w);
  }
  fg[idx] = __fdiv_rn(acc, 16.0f);                   // exact (pow2)
}

// ---------------- coarse_scores = 16x16 stride-1 window mean ----------------
// Register-blocked: 4 outputs per thread along ox share 19-wide row loads.
// Each output's add chain stays wy-outer / wx-inner, bit-identical to XLA.
// Also initializes the encoded min/max slots for k_resize's atomics.
__global__ void k_cs(const float* __restrict__ fg, float* __restrict__ cs,
                     unsigned* __restrict__ mm) {
  if (blockIdx.x == 0 && threadIdx.x < 16)
    mm[threadIdx.x] = (threadIdx.x < 8) ? 0xFFFFFFFFu : 0u;   // min=+inf, max=-inf

  int idx = blockIdx.x * 256 + threadIdx.x;
  const int TOT = B_ * CSW * CSG;                    // 117608
  if (idx >= TOT) return;
  int b = idx / (CSW * CSG); int rem = idx % (CSW * CSG);
  int oy = rem / CSG; int ox0 = (rem % CSG) * 4;
  int nk = min(4, CSW - ox0);                        // 4, or 1 at ox0=240
  int lv = nk + 15;                                  // valid loads per row
  const float* p = fg + (size_t)b * 65536 + (size_t)oy * 256 + ox0;

  float acc[4] = {0.0f, 0.0f, 0.0f, 0.0f};
  for (int wy = 0; wy < 16; ++wy) {
    const float* r = p + wy * 256;
    float v[19];
    #pragma unroll
    for (int x = 0; x < 19; ++x) { v[x] = 0.0f; if (x < lv) v[x] = r[x]; }
    #pragma unroll
    for (int k = 0; k < 4; ++k) {
      if (k < nk) {
        #pragma unroll
        for (int wx = 0; wx < 16; ++wx) acc[k] = __fadd_rn(acc[k], v[k + wx]);
      }
    }
  }
  float* co = cs + (size_t)b * (CSW * CSW) + (size_t)oy * CSW + ox0;
  #pragma unroll
  for (int k = 0; k < 4; ++k)
    if (k < nk) co[k] = __fdiv_rn(acc[k], 256.0f);   // exact (pow2)
}

// ---------------- bilinear resize 241x241 -> 121x121 + fused min/max ----------------
// grid (58, 8): blockIdx.y = batch, so each block reduces a single batch.
__global__ void k_resize(const float* __restrict__ cs, float* __restrict__ flat,
                         unsigned* __restrict__ mm) {
  __shared__ unsigned smn[256], smx[256];
  int b = blockIdx.y;
  int rem = blockIdx.x * 256 + threadIdx.x;
  int tid = threadIdx.x;
  unsigned mn = 0xFFFFFFFFu, mx = 0u;

  if (rem < NPB) {
    int oy = rem / GW; int ox = rem % GW;
    const float SCALE = (float)(241.0 / 121.0);      // f64 const -> f32

    float cy = __fsub_rn(__fmul_rn(__fadd_rn((float)oy, 0.5f), SCALE), 0.5f);
    cy = fminf(fmaxf(cy, 0.0f), 240.0f);
    int y0 = (int)floorf(cy); int y1 = min(y0 + 1, 240);
    float wy = __fsub_rn(cy, (float)y0);

    float cx = __fsub_rn(__fmul_rn(__fadd_rn((float)ox, 0.5f), SCALE), 0.5f);
    cx = fminf(fmaxf(cx, 0.0f), 240.0f);
    int x0 = (int)floorf(cx); int x1 = min(x0 + 1, 240);
    float wx = __fsub_rn(cx, (float)x0);

    const float* base = cs + (size_t)b * (CSW * CSW);
    float v00 = base[y0 * CSW + x0];
    float v01 = base[y0 * CSW + x1];
    float v10 = base[y1 * CSW + x0];
    float v11 = base[y1 * CSW + x1];
    float omwx = __fsub_rn(1.0f, wx), omwy = __fsub_rn(1.0f, wy);
    float top = __fadd_rn(__fmul_rn(v00, omwx), __fmul_rn(v01, wx));
    float bot = __fadd_rn(__fmul_rn(v10, omwx), __fmul_rn(v11, wx));
    float val = __fadd_rn(__fmul_rn(top, omwy), __fmul_rn(bot, wy));
    flat[(size_t)b * NPB + rem] = val;
    unsigned o = enc_f(val);
    mn = o; mx = o;
  }
  smn[tid] = mn; smx[tid] = mx; __syncthreads();
  for (int s = 128; s > 0; s >>= 1) {
    if (tid < s) {
      smn[tid] = min(smn[tid], smn[tid + s]);
      smx[tid] = max(smx[tid], smx[tid + s]);
    }
    __syncthreads();
  }
  if (tid == 0) {
    atomicMin(&mm[b], smn[0]);                       // device-scope, exact
    atomicMax(&mm[8 + b], smx[0]);
  }
}

// ---------------- threefry2x32, key (0,42), both output lanes ----------------
__device__ __forceinline__ void tf2(unsigned c0, unsigned c1,
                                    unsigned* o0, unsigned* o1) {
  const unsigned ks0 = 0u, ks1 = 42u, ks2 = 0x1BD11BDAu ^ 0u ^ 42u;
  unsigned x0 = c0 + ks0, x1 = c1 + ks1;
#define RND(r) { x0 += x1; x1 = (x1 << r) | (x1 >> (32 - r)); x1 ^= x0; }
  RND(13) RND(15) RND(26) RND(6)   x0 += ks1; x1 += ks2 + 1u;
  RND(17) RND(29) RND(16) RND(24)  x0 += ks2; x1 += ks0 + 2u;
  RND(13) RND(15) RND(26) RND(6)   x0 += ks0; x1 += ks1 + 3u;
  RND(17) RND(29) RND(16) RND(24)  x0 += ks1; x1 += ks2 + 4u;
  RND(13) RND(15) RND(26) RND(6)   x0 += ks2; x1 += ks0 + 5u;
#undef RND
  *o0 = x0; *o1 = x1;
}

// ---------------- phase A: fused keys + register-bitonic segment sort ----------------
// 128 blocks, 256 threads, 4 elements/thread in REGISTERS (i = q*256+tid).
// Exchange routing: j>=256 -> thread-local register swap; j in {128,64} ->
// LDS (only 7 such passes need barriers); j<=32 -> __shfl_xor (wave-internal,
// barrier-free). Full ascending sort of unique keys == LDS bitonic's result.
// All real keys > 0, so 0-padding sorts strictly below; 256 < 901 real/seg.
__global__ void k_part(const float* __restrict__ flat, const unsigned* __restrict__ mm,
                       unsigned long long* __restrict__ cand) {
  __shared__ unsigned long long sm[1024];
  int blk = blockIdx.x;                 // b*16 + s
  int b = blk >> 4, s = blk & 15;
  int base = s * SEGLEN;
  int len = min(SEGLEN, NPB - base);
  int tid = threadIdx.x;

  float smin = dec_f(mm[b]), smax = dec_f(mm[8 + b]);
  float rng = fmaxf(__fsub_rn(smax, smin), 1e-6f);

  unsigned long long e[4];
  #pragma unroll
  for (int q = 0; q < 4; ++q) {
    int i = q * 256 + tid;
    unsigned long long kv = 0ull;
    if (i < len) {
      int j = base + i;
      int idx = b * NPB + j;
      float scaled = __fdiv_rn(__fdiv_rn(__fsub_rn(flat[idx], smin), rng), 0.1f);

      // JAX partitionable threefry: bits = x0 ^ x1 of tf2(key=(0,42), ctr=(0,idx))
      unsigned o0, o1;
      tf2(0u, (unsigned)idx, &o0, &o1);
      unsigned bits = o0 ^ o1;

      unsigned m = bits >> 9;
      float u = (m == 0u) ? 1.17549435e-38f
                          : __fsub_rn(__uint_as_float(0x3f800000u | m), 1.0f);
      // g = -log(-log(u)), each log evaluated in f64 then rounded to f32
      float l1 = (float)::log((double)u);
      float a  = -l1;
      float l2 = (float)::log((double)a);
      float g  = -l2;

      float tot = __fadd_rn(scaled, g);
      unsigned o = enc_f(tot);
      kv = ((unsigned long long)o << 32) | (unsigned long long)((unsigned)j ^ 0xFFFFFFFFu);
    }
    e[q] = kv;
  }

  // bitonic sort ascending over 1024 (register/LDS/shuffle hybrid)
  for (int ksz = 2; ksz <= 1024; ksz <<= 1) {
    for (int j = ksz >> 1; j > 0; j >>= 1) {
      if (j >= 256) {
        int dq = j >> 8;                            // 1 or 2
        #pragma unroll
        for (int q = 0; q < 4; ++q) {
          if ((q & dq) == 0) {
            int q2 = q | dq;
            int i0 = q * 256 + tid;
            bool up = ((i0 & ksz) == 0);
            unsigned long long a = e[q], c = e[q2];
            unsigned long long mn = a < c ? a : c, mx = a < c ? c : a;
            e[q]  = up ? mn : mx;
            e[q2] = up ? mx : mn;
          }
        }
      } else if (j >= 64) {
        #pragma unroll
        for (int q = 0; q < 4; ++q) sm[q * 256 + tid] = e[q];
        __syncthreads();
        #pragma unroll
        for (int q = 0; q < 4; ++q) {
          int i = q * 256 + tid;
          unsigned long long a = e[q], c = sm[i ^ j];
          bool up = ((i & ksz) == 0);
          bool lowside = ((i & j) == 0);
          bool take_min = (lowside == up);
          unsigned long long mn = a < c ? a : c, mx = a < c ? c : a;
          e[q] = take_min ? mn : mx;
        }
        __syncthreads();
      } else {
        #pragma unroll
        for (int q = 0; q < 4; ++q) {
          int i = q * 256 + tid;
          unsigned long long a = e[q];
          unsigned long long c = __shfl_xor(a, j, 64);
          bool up = ((i & ksz) == 0);
          bool lowside = ((i & j) == 0);
          bool take_min = (lowside == up);
          unsigned long long mn = a < c ? a : c, mx = a < c ? c : a;
          e[q] = take_min ? mn : mx;
        }
      }
    }
  }
  // ranks 768..1023 (largest 256) live in e[3]; descending: cand[255-tid]
  cand[(size_t)blk * 256 + (255 - tid)] = e[3];
}

// ---------------- phase B: wave-owned prune-merge 16 lists -> top-256 ----------------
// One WAVE owns each pair-merge: 256 elems = 4 regs/lane (i = e*64 + lane).
// Prune c[i]=max(A[i],B[255-i]) reads LDS; the descending clean is 2 register
// stages (j=128,64) + 6 shuffle stages (j<=32) — no barriers inside a round.
// Only 4 inter-round barriers. Unique keys -> output bit-identical to before.
__global__ void k_merge(const unsigned long long* __restrict__ cand,
                        float* __restrict__ coords) {
  __shared__ unsigned long long sm[4096];
  int b = blockIdx.x, tid = threadIdx.x;
  int w = tid >> 6, l = tid & 63;
  const ulonglong2* cb2 = (const ulonglong2*)(cand + (size_t)b * 4096);
  for (int t = tid; t < 2048; t += 256) {
    ulonglong2 v = cb2[t];
    sm[2 * t] = v.x; sm[2 * t + 1] = v.y;
  }
  __syncthreads();

  int g = 1;                            // slot gap between live lists
  for (int m = NSEG; m > 1; m >>= 1, g <<= 1) {
    int half = m >> 1;
    for (int p = w; p < half; p += 4) {
      int A = (2 * p) * g * 256, Bb = (2 * p + 1) * g * 256;
      unsigned long long r[4];
      // prune: top-256 of pair, bitonic
      #pragma unroll
      for (int eIdx = 0; eIdx < 4; ++eIdx) {
        int i = eIdx * 64 + l;
        unsigned long long a = sm[A + i], c = sm[Bb + 255 - i];
        r[eIdx] = a > c ? a : c;
      }
      // clean descending, j=128: pairs (e, e^2)
      {
        unsigned long long a0 = r[0], a2 = r[2];
        r[0] = a0 > a2 ? a0 : a2; r[2] = a0 > a2 ? a2 : a0;
        unsigned long long a1 = r[1], a3 = r[3];
        r[1] = a1 > a3 ? a1 : a3; r[3] = a1 > a3 ? a3 : a1;
      }
      // j=64: pairs (e, e^1)
      {
        unsigned long long a0 = r[0], a1 = r[1];
        r[0] = a0 > a1 ? a0 : a1; r[1] = a0 > a1 ? a1 : a0;
        unsigned long long a2 = r[2], a3 = r[3];
        r[2] = a2 > a3 ? a2 : a3; r[3] = a2 > a3 ? a3 : a2;
      }
      // j=32..1: wave-internal shuffles (descending: low side keeps max)
      #pragma unroll
      for (int j = 32; j > 0; j >>= 1) {
        #pragma unroll
        for (int eIdx = 0; eIdx < 4; ++eIdx) {
          unsigned long long a = r[eIdx];
          unsigned long long c = __shfl_xor(a, j, 64);
          bool low = ((l & j) == 0);
          unsigned long long mx = a > c ? a : c, mn = a > c ? c : a;
          r[eIdx] = low ? mx : mn;
        }
      }
      // write result back to A's slot
      #pragma unroll
      for (int eIdx = 0; eIdx < 4; ++eIdx) sm[A + eIdx * 64 + l] = r[eIdx];
    }
    __syncthreads();
  }

  unsigned long long key = sm[tid];     // descending -> tid = rank
  unsigned j = ((unsigned)(key & 0xFFFFFFFFull)) ^ 0xFFFFFFFFu;
  int row = j / GW, col = j % GW;
  coords[((size_t)b * KSEL + tid) * 2 + 0] = (float)(row * 8);
  coords[((size_t)b * KSEL + tid) * 2 + 1] = (float)(col * 8);
}

// ---------------- gather patches + label patches (float4, NT stores) ----------------
// w = col*8 -> 32B-aligned row starts; all accesses are aligned float4.
// Outputs are streamed (never re-read) -> nontemporal stores keep L2 for
// the scattered image reads. NT builtin needs a native vector type (floatx4).
__global__ void k_gather(const float* __restrict__ image, const float* __restrict__ labels,
                         float* __restrict__ out) {
  int bk = blockIdx.x;                 // b*256 + k
  int b = bk >> 8;
  const float* coords = out + COORD_OFF;
  int h = (int)coords[(size_t)bk * 2 + 0];
  int w = (int)coords[(size_t)bk * 2 + 1];

  const float* imgb = image + (size_t)b * 3145728;
  floatx4* po = (floatx4*)(out + PATCH_OFF + (size_t)bk * 12288);
  for (int t = threadIdx.x; t < 3072; t += 256) {
    int c = t >> 10, rem = t & 1023, y = rem >> 4, x4 = rem & 15;
    floatx4 v = *(const floatx4*)(imgb + (size_t)c * 1048576 +
                                  (size_t)(h + y) * 1024 + w + x4 * 4);
    __builtin_nontemporal_store(v, &po[t]);
  }
  const float* labb = labels + (size_t)b * 1048576;
  floatx4* lo = (floatx4*)(out + LABEL_OFF + (size_t)bk * 4096);
  for (int t = threadIdx.x; t < 1024; t += 256) {
    int y = t >> 4, x4 = t & 15;
    floatx4 v = *(const floatx4*)(labb + (size_t)(h + y) * 1024 + w + x4 * 4);
    __builtin_nontemporal_store(v, &lo[t]);
  }
}

extern "C" void kernel_launch(void* const* d_in, const int* in_sizes, int n_in,
                              void* d_out, int out_size, void* d_ws, size_t ws_size,
                              hipStream_t stream) {
  const float* image  = (const float*)d_in[0];   // (8,3,1024,1024)
  const float* labels = (const float*)d_in[1];   // (8,1,1024,1024)
  float* out = (float*)d_out;

  float* fg   = out + FG_OFF;
  float* cs   = out + CS_OFF;
  float* flat = out + FLAT_OFF;
  unsigned* mm = (unsigned*)(out + MM_OFF);
  unsigned long long* cand = (unsigned long long*)(out + CAND_OFF);
  float* coords = out + COORD_OFF;

  k_fg<<<2048, 256, 0, stream>>>(labels, fg);
  k_cs<<<(B_ * CSW * CSG + 255) / 256, 256, 0, stream>>>(fg, cs, mm);
  k_resize<<<dim3((NPB + 255) / 256, B_), 256, 0, stream>>>(cs, flat, mm);
  k_part<<<B_ * NSEG, 256, 0, stream>>>(flat, mm, cand);
  k_merge<<<B_, 256, 0, stream>>>(cand, coords);
  k_gather<<<2048, 256, 0, stream>>>(image, labels, out);
}